// Round 8
// baseline (134.468 us; speedup 1.0000x reference)
//
#include <hip/hip_runtime.h>
#include <stdint.h>

#define T_LEN 2048

typedef __attribute__((ext_vector_type(8))) short bf16x8;
typedef __attribute__((ext_vector_type(16))) float f32x16;

// RNE fp32 pair -> packed bf16x2 (inputs finite normals)
static __device__ __forceinline__ unsigned pack_bf16(float a, float b) {
    unsigned ua = __float_as_uint(a);
    unsigned ub = __float_as_uint(b);
    ua = (ua + 0x7fffu + ((ua >> 16) & 1u)) >> 16;
    ub = (ub + 0x7fffu + ((ub >> 16) & 1u));
    return (ua & 0xffffu) | (ub & 0xffff0000u);
}

// 2^x on the transcendental pipe (scores carry log2e folded in from prepack)
static __device__ __forceinline__ float fexp2(float x) {
#if __has_builtin(__builtin_amdgcn_exp2f)
    return __builtin_amdgcn_exp2f(x);
#else
    float r; asm("v_exp_f32 %0, %1" : "=v"(r) : "v"(x)); return r;
#endif
}

// v_permlane32_swap_b32 a, b (in-place, inline asm; HW-verified R6):
//   a_new = {a.lo, b.lo}, b_new = {a.hi, b.hi}  (a.hi <-> b.lo)
static __device__ __forceinline__ void swap32(unsigned& a, unsigned& b) {
    asm("v_permlane32_swap_b32 %0, %1" : "+v"(a), "+v"(b));
}

// ---------------------------------------------------------------------------
// Prepack — now writes MFMA-FRAGMENT-ORDERED files so attn can load operand
// fragments directly global->VGPR as coalesced dwordx4 (lane*16 contiguous):
//
//   Q/K file (256KB/head): [g = t>>5][kb 0..3][lane = h*32 + (t&31)][w 0..3]
//     word (g,kb,lane,w) = bf16x2 of columns c = (kb*2+h)*8 + 2w, +1, row t.
//     A wave loading base + g*4096 + kb*1024 + lane*16 gets exactly the
//     B-operand fragment kf[kb] for rows g*32..+32 (lane l: row g*32+(l&31),
//     chunk kb*2+(l>>5)).  Q scaled 0.125*log2(e).
//   V file (256KB/head): [sTile st][wsx][kb2][ct][lane = h*32 + (c&31)][w]
//     word = bf16x2 of s = st*64 + (wsx*4+kb2*2+h)*8 + 2w, +1, V-row c.
//     Wave loads base + st*8192 + wsx*4096 + kb2*2048 + ct*1024 + lane*16.
// No swizzle needed (no LDS banking in the consumer).
// ---------------------------------------------------------------------------
__global__ __launch_bounds__(256)
void prepack(const float* __restrict__ qkv, char* __restrict__ ws)
{
    __shared__ float tile[64 * 130];
    const int tid = threadIdx.x;
    const int b = blockIdx.x;

    if (b < 1024) {                       // ---- Q / K transpose
        const int isK  = b >> 9;
        const int bb   = b & 511;
        const int head = bb >> 4, chunk = bb & 15;
        const float* src = qkv + (size_t)head * 192 * T_LEN
                               + (size_t)(isK ? 64 : 0) * T_LEN;
        const int t0g = chunk * 128;
        const float scale = isK ? 1.0f : 0.18033688f;
#pragma unroll
        for (int i = 0; i < 8; ++i) {
            int p = i * 256 + tid;
            int t4 = p & 31, c = p >> 5;
            float4 v = *(const float4*)(src + (size_t)c * T_LEN + t0g + 4 * t4);
            int a = c * 130 + 4 * t4;
            *(float2*)&tile[a]     = make_float2(v.x, v.y);
            *(float2*)&tile[a + 2] = make_float2(v.z, v.w);
        }
        __syncthreads();
        // dst base: t0g*32 words == (t0g>>5)*1024 -> local g = t>>5 is correct
        unsigned* dst = (unsigned*)ws + (size_t)isK * 2097152
                      + (size_t)head * 65536 + (size_t)t0g * 32;
#pragma unroll
        for (int i = 0; i < 16; ++i) {
            int cp = tid & 31, t = i * 8 + (tid >> 5);   // t local 0..127
            float f0 = tile[(2 * cp) * 130 + t] * scale;
            float f1 = tile[(2 * cp + 1) * 130 + t] * scale;
            // c-pair cp: chunk = cp>>2, kb = cp>>3, h = (cp>>2)&1, w = cp&3
            dst[(t >> 5) * 1024 + (cp >> 3) * 256 + ((cp >> 2) & 1) * 128
                + (t & 31) * 4 + (cp & 3)] = pack_bf16(f0, f1);
        }
    } else {                              // ---- V fragment reorder
        const int b3 = b - 1024;
        const int head = b3 >> 5, st = b3 & 31;
        const float* src = qkv + (size_t)head * 192 * T_LEN + (size_t)128 * T_LEN;
        const int s0 = st * 64;
        unsigned* dst = (unsigned*)(ws + 16777216) + (size_t)b3 * 2048;
#pragma unroll
        for (int i = 0; i < 8; ++i) {
            int p = i * 256 + tid;
            int s2 = p & 31, c = p >> 5;
            float2 v = *(const float2*)(src + (size_t)c * T_LEN + s0 + 2 * s2);
            // s-pair s2: chunk = s2>>2 = wsx*4+kb2*2+h, w = s2&3; row c
            dst[(s2 >> 4) * 1024 + ((s2 >> 3) & 1) * 512 + (c >> 5) * 256
                + ((s2 >> 2) & 1) * 128 + (c & 31) * 4 + (s2 & 3)]
                = pack_bf16(v.x, v.y);
        }
    }
}

// ---------------------------------------------------------------------------
// Main: flash attention, 32x32x16 MFMA, operand-swapped QK, permlane exchange.
// BARRIER-FREE main loop: all K/V/Q operand fragments are loaded directly
// global->VGPR (coalesced dwordx4 from the fragment-ordered files). No LDS
// staging, no __syncthreads in the loop -> waves drift out of phase and one
// wave's softmax (VALU) overlaps another's MFMA. L1 dedupes the 4x fragment
// reuse across wt2-waves (16KB live set/block; co-resident blocks share a
// head via head = blockIdx>>4). LDS used only for the epilogue combine.
// 8 waves x 512 thr, wave (wt2, wsx) owns 32t x 32s per iteration.
// ---------------------------------------------------------------------------
__global__ __launch_bounds__(512, 4)
void attn_fwd(const char* __restrict__ ws, float* __restrict__ out)
{
    __shared__ char smem[33792];        // Ob 64c x 128t fp32 (32KB) + Lb (1KB)
    const int tid  = threadIdx.x;
    const int wave = tid >> 6, lane = tid & 63;
    const int l31  = lane & 31, h = lane >> 5;
    const int wt2  = wave & 3;          // t-quarter (32 t)
    const int wsx  = wave >> 2;         // s-half (32 s per iter)
    const int head = blockIdx.x >> 4, tb = blockIdx.x & 15;

    const char* qsrc = ws + (size_t)head * 262144 + ((size_t)(tb * 4 + wt2)) * 4096;
    const char* ksrc = ws + 8388608  + (size_t)head * 262144 + (size_t)wsx * 4096;
    const char* vsrc = ws + 16777216 + (size_t)head * 262144 + (size_t)wsx * 4096;

    float* Ob = (float*)smem;
    float* Lb = (float*)(smem + 32768);

    // Q fragments: direct coalesced loads (one-time)
    bf16x8 qf[4];
#pragma unroll
    for (int kb = 0; kb < 4; ++kb)
        qf[kb] = *(const bf16x8*)(qsrc + kb * 1024 + lane * 16);

    f32x16 acc[2];                      // [ct], D = O^T[c][t] partial (s-half)
#pragma unroll
    for (int ct = 0; ct < 2; ++ct)
#pragma unroll
        for (int r = 0; r < 16; ++r) acc[ct][r] = 0.f;
    float lp = 0.f;

    for (int i = 0; i < 32; ++i) {
        // ---- K fragments for s-group 2i+wsx: 4 coalesced dwordx4
        const char* kp = ksrc + (size_t)i * 8192;   // (2i+wsx)*4096
        bf16x8 kf0 = *(const bf16x8*)(kp);
        bf16x8 kf1 = *(const bf16x8*)(kp + 1024 + lane * 16 - lane * 16 + 1024 - 1024);
        kf1 = *(const bf16x8*)(kp + 1024 + lane * 16);
        bf16x8 kf2 = *(const bf16x8*)(kp + 2048 + lane * 16);
        bf16x8 kf3 = *(const bf16x8*)(kp + 3072 + lane * 16);
        kf0 = *(const bf16x8*)(kp + lane * 16);

        // ---- QK^T (A=K): S^T rows s = (2i+wsx)*32 + pat, cols t
        f32x16 sc;
#pragma unroll
        for (int r = 0; r < 16; ++r) sc[r] = 0.f;
        sc = __builtin_amdgcn_mfma_f32_32x32x16_bf16(kf0, qf[0], sc, 0, 0, 0);
        sc = __builtin_amdgcn_mfma_f32_32x32x16_bf16(kf1, qf[1], sc, 0, 0, 0);
        sc = __builtin_amdgcn_mfma_f32_32x32x16_bf16(kf2, qf[2], sc, 0, 0, 0);
        sc = __builtin_amdgcn_mfma_f32_32x32x16_bf16(kf3, qf[3], sc, 0, 0, 0);

        // ---- softmax (pre-scaled by log2e -> raw 2^x) + bf16 truncation pack
        union P8 { unsigned u[8]; bf16x8 v[2]; };
        P8 P;
#pragma unroll
        for (int d = 0; d < 8; ++d) {
            unsigned a0 = __float_as_uint(fexp2(sc[2 * d]))     & 0xffff0000u;
            unsigned a1 = __float_as_uint(fexp2(sc[2 * d + 1])) & 0xffff0000u;
            lp += __uint_as_float(a0) + __uint_as_float(a1);
            P.u[d] = __builtin_amdgcn_perm(a1, a0, 0x07060302u);
        }
        swap32(P.u[0], P.u[2]); swap32(P.u[1], P.u[3]);
        swap32(P.u[4], P.u[6]); swap32(P.u[5], P.u[7]);

        // ---- PV: O^T[c][t] += V[c][s] * P[t][s]; vf direct coalesced loads
        const char* vp = vsrc + (size_t)i * 8192;
#pragma unroll
        for (int kb2 = 0; kb2 < 2; ++kb2) {
            const bf16x8 pfv = kb2 ? P.v[1] : P.v[0];
#pragma unroll
            for (int ct = 0; ct < 2; ++ct) {
                bf16x8 vf = *(const bf16x8*)(vp + kb2 * 2048 + ct * 1024 + lane * 16);
                acc[ct] = __builtin_amdgcn_mfma_f32_32x32x16_bf16(vf, pfv, acc[ct], 0, 0, 0);
            }
        }
    }

    // ---- l: reduce over h, publish per s-half (one wave per (wsx,wt2))
    float lt = lp + __shfl_xor(lp, 32);
    if (h == 0) Lb[wsx * 128 + wt2 * 32 + l31] = lt;

    // ---- O: s-half-1 waves stash partials
    if (wsx == 1) {
#pragma unroll
        for (int ct = 0; ct < 2; ++ct)
#pragma unroll
            for (int r = 0; r < 16; ++r) {
                int c = ct * 32 + (r & 3) + 8 * (r >> 2) + 4 * h;
                Ob[c * 128 + wt2 * 32 + l31] = acc[ct][r];
            }
    }
    __syncthreads();

    if (wsx == 0) {
        const float li = 1.0f / (Lb[wt2 * 32 + l31] + Lb[128 + wt2 * 32 + l31]);
#pragma unroll
        for (int ct = 0; ct < 2; ++ct)
#pragma unroll
            for (int r = 0; r < 16; ++r) {
                int c = ct * 32 + (r & 3) + 8 * (r >> 2) + 4 * h;
                float v = acc[ct][r] + Ob[c * 128 + wt2 * 32 + l31];
                out[((size_t)head * 64 + c) * T_LEN + tb * 128 + wt2 * 32 + l31]
                    = v * li;
            }
    }
}

extern "C" void kernel_launch(void* const* d_in, const int* in_sizes, int n_in,
                              void* d_out, int out_size, void* d_ws, size_t ws_size,
                              hipStream_t stream) {
    const float* qkv = (const float*)d_in[0];
    float* out = (float*)d_out;
    char* ws = (char*)d_ws;   // 24 MB
    hipLaunchKernelGGL(prepack, dim3(2048), dim3(256), 0, stream, qkv, ws);
    hipLaunchKernelGGL(attn_fwd, dim3(512), dim3(512), 0, stream, ws, out);
}